// Round 4
// baseline (1229.028 us; speedup 1.0000x reference)
//
#include <hip/hip_runtime.h>

// ConvLSTM fp32, round 4 (= round 3 resubmit after infra failure):
// software-pipelined weight staging (reg prefetch + LDS ping-pong, 1
// barrier/chunk) in both convs; gates k0-flag removes the hx/cx memsets and
// the hx buffer; fast-math transcendentals in gates/head.

#define WSTRIDE 442368   // per-layer conv weight elements: 27*64*256

__device__ __forceinline__ float wred_sum(float v) {
    #pragma unroll
    for (int o = 32; o > 0; o >>= 1) v += __shfl_down(v, o, 64);
    return __shfl(v, 0, 64);
}
__device__ __forceinline__ float fsig(float x)  { return 1.f / (1.f + __expf(-x)); }
__device__ __forceinline__ float ftanh(float x) { return 1.f - 2.f / (__expf(2.f*x) + 1.f); }

// h[nc][s][vox][ch] = emb[tok][ch]
__global__ __launch_bounds__(256) void embed_kernel(
    const int* __restrict__ code, const int* __restrict__ ncode,
    const float* __restrict__ emb, float* __restrict__ h)
{
    int e = blockIdx.x * 256 + threadIdx.x;   // < 2*7*512*64 = 458752
    int ch = e & 63;
    int pos = e >> 6;            // nc*7*512 + s*512 + vox
    int vox = pos & 511;
    int t = pos >> 9;            // nc*7 + s
    int s = t % 7, nc = t / 7;
    int tok = (s < 5) ? code[(nc*5 + s)*512 + vox]
                      : ncode[(nc*3 + (s-5))*512 + vox];
    h[e] = emb[tok*64 + ch];
}

// 3x3x3 SAME conv, Cin=64 -> Cout=256, raw output + bias.
// x: [nslabs][512][64], wt: [27][64][256], y: [nslabs][512][256]
// grid = nslabs*8*4; block = (u-plane 64 vox) x (64 couts).
// Weight staging pipelined: chunk = [9 taps][4 ci][64 co] = 9216 B, reg
// prefetch of chunk k+1 overlaps compute of chunk k; LDS ping-pong.
__global__ __launch_bounds__(256) void conv_kernel(
    const float* __restrict__ x, const float* __restrict__ wt,
    const float* __restrict__ bias, float* __restrict__ y)
{
    __shared__ float xs[3][64][65];                 // ~49.9 KB
    __shared__ alignas(16) float ws[2][2304];       // 2 x 9 KB
    const int b = blockIdx.x;
    const int cg   = b & 3;
    const int u    = (b >> 2) & 7;
    const int slab = b >> 5;
    const int t = threadIdx.x;

    #pragma unroll
    for (int du = 0; du < 3; ++du) {
        const int uu = u + du - 1;
        const bool ok = (uu >= 0) && (uu < 8);
        const float4* xp4 = (const float4*)(x + (size_t)(slab*512 + uu*64)*64);
        #pragma unroll
        for (int p = 0; p < 4; ++p) {
            int q = p*256 + t;                  // float4 index, vox = q>>4
            float4 v = {0.f, 0.f, 0.f, 0.f};
            if (ok) v = xp4[q];
            int vox = q >> 4, ci0 = (q & 15) * 4;
            xs[du][ci0+0][vox] = v.x;
            xs[du][ci0+1][vox] = v.y;
            xs[du][ci0+2][vox] = v.z;
            xs[du][ci0+3][vox] = v.w;
        }
    }

    const int co4 = t & 15, vg = t >> 4;
    const int co = cg*64 + co4*4;
    const int v0 = (vg >> 2) << 1;
    const int w0 = (vg & 3) << 1;

    int xoff[16];
    #pragma unroll
    for (int a = 0; a < 4; ++a)
        #pragma unroll
        for (int bb = 0; bb < 4; ++bb) {
            int vv = v0 - 1 + a, ww = w0 - 1 + bb;
            xoff[a*4+bb] = (vv >= 0 && vv < 8 && ww >= 0 && ww < 8) ? (vv*8 + ww) : -1;
        }

    // prefetch chunk 0: f = tap*256 + cii*64 + co, f = 4*(p*256+t)
    float4 wr[3];
    {
        const float* base = wt + (size_t)cg*64;     // du=0, c4=0
        #pragma unroll
        for (int p = 0; p < 3; ++p) {
            int q = p*256 + t;
            if (p < 2 || t < 64) {
                int f = q*4;
                wr[p] = *(const float4*)(base +
                    (size_t)((f>>8)*64 + ((f>>6)&3))*256 + (f & 63));
            }
        }
    }

    float acc[4][4] = {};
    for (int chunk = 0; chunk < 48; ++chunk) {
        float* wb = ws[chunk & 1];
        #pragma unroll
        for (int p = 0; p < 3; ++p) {
            int q = p*256 + t;
            if (p < 2 || t < 64) *(float4*)(wb + q*4) = wr[p];
        }
        __syncthreads();
        if (chunk < 47) {
            int nc = chunk + 1;
            int ndu = nc >> 4, nc4 = nc & 15;
            const float* base = wt + (size_t)(ndu*576 + nc4*4)*256 + cg*64;
            #pragma unroll
            for (int p = 0; p < 3; ++p) {
                int q = p*256 + t;
                if (p < 2 || t < 64) {
                    int f = q*4;
                    wr[p] = *(const float4*)(base +
                        (size_t)((f>>8)*64 + ((f>>6)&3))*256 + (f & 63));
                }
            }
        }
        const int du = chunk >> 4, c4 = chunk & 15;
        const float* xb = &xs[du][0][0];
        #pragma unroll
        for (int cii = 0; cii < 4; ++cii) {
            const int ci = c4*4 + cii;
            float xpv[16];
            #pragma unroll
            for (int q = 0; q < 16; ++q)
                xpv[q] = (xoff[q] >= 0) ? xb[ci*65 + xoff[q]] : 0.f;
            const float* wrow = wb + cii*64 + co4*4;
            #pragma unroll
            for (int dv = 0; dv < 3; ++dv)
                #pragma unroll
                for (int dw = 0; dw < 3; ++dw) {
                    const float4 wv = *(const float4*)(wrow + (dv*3 + dw)*256);
                    #pragma unroll
                    for (int j = 0; j < 4; ++j) {
                        float xv = xpv[((j>>1)+dv)*4 + ((j&1)+dw)];
                        acc[0][j] = fmaf(wv.x, xv, acc[0][j]);
                        acc[1][j] = fmaf(wv.y, xv, acc[1][j]);
                        acc[2][j] = fmaf(wv.z, xv, acc[2][j]);
                        acc[3][j] = fmaf(wv.w, xv, acc[3][j]);
                    }
                }
        }
    }
    const float4 bv = *(const float4*)(bias + co);
    #pragma unroll
    for (int j = 0; j < 4; ++j) {
        int v = v0 + (j>>1), w = w0 + (j&1);
        float4 o;
        o.x = acc[0][j] + bv.x; o.y = acc[1][j] + bv.y;
        o.z = acc[2][j] + bv.z; o.w = acc[3][j] + bv.w;
        *(float4*)(y + (size_t)((slab*512 + u*64 + v*8 + w)*256 + co)) = o;
    }
}

// Recurrent conv: reads h[., k] directly; cout split 16 ways, K (ci) split
// 4-way with LDS reduction -> 256 blocks (1/CU). Same pipelined staging.
// chunk = [9 taps][4 kp][4 ci][16 co] = 9216 B.
__global__ __launch_bounds__(256) void conv_rec_kernel(
    const float* __restrict__ h, int k,
    const float* __restrict__ wt,
    const float* __restrict__ bias, float* __restrict__ y)
{
    __shared__ float xs[3][64][65];
    __shared__ alignas(16) float ws[2][2304];
    const int b = blockIdx.x;          // 2*8*16 = 256
    const int cg   = b & 15;
    const int u    = (b >> 4) & 7;
    const int slab = b >> 7;
    const int t = threadIdx.x;

    #pragma unroll
    for (int du = 0; du < 3; ++du) {
        const int uu = u + du - 1;
        const bool ok = (uu >= 0) && (uu < 8);
        const float4* xp4 = (const float4*)(h + ((size_t)(slab*7 + k)*512 + uu*64)*64);
        #pragma unroll
        for (int p = 0; p < 4; ++p) {
            int q = p*256 + t;
            float4 v = {0.f, 0.f, 0.f, 0.f};
            if (ok) v = xp4[q];
            int vox = q >> 4, ci0 = (q & 15) * 4;
            xs[du][ci0+0][vox] = v.x;
            xs[du][ci0+1][vox] = v.y;
            xs[du][ci0+2][vox] = v.z;
            xs[du][ci0+3][vox] = v.w;
        }
    }

    const int kp = t >> 6;             // ci quarter
    const int lane = t & 63;
    const int coq = lane & 3, vg = lane >> 2;
    const int co = cg*16 + coq*4;
    const int v0 = (vg >> 2) << 1;
    const int w0 = (vg & 3) << 1;

    int xoff[16];
    #pragma unroll
    for (int a = 0; a < 4; ++a)
        #pragma unroll
        for (int bb = 0; bb < 4; ++bb) {
            int vv = v0 - 1 + a, ww = w0 - 1 + bb;
            xoff[a*4+bb] = (vv >= 0 && vv < 8 && ww >= 0 && ww < 8) ? (vv*8 + ww) : -1;
        }

    // prefetch chunk 0: f = tap*256 + kpp*64 + cii*16 + co, f = 4*(p*256+t)
    float4 wr[3];
    {
        const float* base = wt + (size_t)cg*16;
        #pragma unroll
        for (int p = 0; p < 3; ++p) {
            int q = p*256 + t;
            if (p < 2 || t < 64) {
                int f = q*4;
                wr[p] = *(const float4*)(base +
                    (size_t)((f>>8)*64 + ((f>>6)&3)*16 + ((f>>4)&3))*256 + (f & 15));
            }
        }
    }

    float acc[4][4] = {};
    for (int chunk = 0; chunk < 12; ++chunk) {
        float* wb = ws[chunk & 1];
        #pragma unroll
        for (int p = 0; p < 3; ++p) {
            int q = p*256 + t;
            if (p < 2 || t < 64) *(float4*)(wb + q*4) = wr[p];
        }
        __syncthreads();
        if (chunk < 11) {
            int nc = chunk + 1;
            int ndu = nc >> 2, nc4 = nc & 3;
            const float* base = wt + (size_t)(ndu*576 + nc4*4)*256 + cg*16;
            #pragma unroll
            for (int p = 0; p < 3; ++p) {
                int q = p*256 + t;
                if (p < 2 || t < 64) {
                    int f = q*4;
                    wr[p] = *(const float4*)(base +
                        (size_t)((f>>8)*64 + ((f>>6)&3)*16 + ((f>>4)&3))*256 + (f & 15));
                }
            }
        }
        const int du = chunk >> 2, c4 = chunk & 3;
        const float* xb = &xs[du][0][0];
        #pragma unroll
        for (int cii = 0; cii < 4; ++cii) {
            const int ci = kp*16 + c4*4 + cii;
            float xpv[16];
            #pragma unroll
            for (int q = 0; q < 16; ++q)
                xpv[q] = (xoff[q] >= 0) ? xb[ci*65 + xoff[q]] : 0.f;
            const float* wrow = wb + kp*64 + cii*16 + coq*4;
            #pragma unroll
            for (int dv = 0; dv < 3; ++dv)
                #pragma unroll
                for (int dw = 0; dw < 3; ++dw) {
                    const float4 wv = *(const float4*)(wrow + (dv*3 + dw)*256);
                    #pragma unroll
                    for (int j = 0; j < 4; ++j) {
                        float xv = xpv[((j>>1)+dv)*4 + ((j&1)+dw)];
                        acc[0][j] = fmaf(wv.x, xv, acc[0][j]);
                        acc[1][j] = fmaf(wv.y, xv, acc[1][j]);
                        acc[2][j] = fmaf(wv.z, xv, acc[2][j]);
                        acc[3][j] = fmaf(wv.w, xv, acc[3][j]);
                    }
                }
        }
    }
    __syncthreads();                    // done reading xs, reuse as reduction buffer
    float* red = &xs[0][0][0];          // need 16*256 = 4096 floats
    #pragma unroll
    for (int a = 0; a < 4; ++a)
        #pragma unroll
        for (int j = 0; j < 4; ++j)
            red[(a*4+j)*256 + t] = acc[a][j];
    __syncthreads();
    if (t < 64) {                       // kp==0 class owns the final sum
        const float4 bv = *(const float4*)(bias + co);
        float fin[16];
        #pragma unroll
        for (int i = 0; i < 16; ++i)
            fin[i] = red[i*256 + t] + red[i*256 + 64 + t]
                   + red[i*256 + 128 + t] + red[i*256 + 192 + t];
        #pragma unroll
        for (int j = 0; j < 4; ++j) {
            int v = v0 + (j>>1), w = w0 + (j&1);
            float4 o;
            o.x = fin[0*4+j] + bv.x; o.y = fin[1*4+j] + bv.y;
            o.z = fin[2*4+j] + bv.z; o.w = fin[3*4+j] + bv.w;
            *(float4*)(y + (size_t)((slab*512 + u*64 + v*8 + w)*256 + co)) = o;
        }
    }
}

// In-place LayerNorm over 256 channels, one wave per row (4 rows/block).
__global__ __launch_bounds__(256) void ln_kernel(
    float* __restrict__ yio, const float* __restrict__ g,
    const float* __restrict__ b)
{
    const int wid = threadIdx.x >> 6, lane = threadIdx.x & 63;
    const int row = blockIdx.x * 4 + wid;
    float4 v = *(const float4*)(yio + (size_t)row*256 + lane*4);
    float mu = wred_sum(v.x + v.y + v.z + v.w) * (1.f/256.f);
    float4 d = { v.x-mu, v.y-mu, v.z-mu, v.w-mu };
    float var = wred_sum(d.x*d.x + d.y*d.y + d.z*d.z + d.w*d.w) * (1.f/256.f);
    float rs = rsqrtf(var + 1e-5f);
    float4 gv = *(const float4*)(g + lane*4);
    float4 bv = *(const float4*)(b + lane*4);
    float4 o = { d.x*rs*gv.x + bv.x, d.y*rs*gv.y + bv.y,
                 d.z*rs*gv.z + bv.z, d.w*rs*gv.w + bv.w };
    *(float4*)(yio + (size_t)row*256 + lane*4) = o;
}

// LSTM cell at step k: LN(gsrc) + gi[k] -> gates -> cx update -> h[., k].
// k0: gsrc is the 256-vector bh (ghat_0 = conv(0)+bh) and cx_old = 0.
__global__ __launch_bounds__(256) void gates_kernel(
    const float* __restrict__ gsrc, int k0, int k,
    const float* __restrict__ gi,
    const float* __restrict__ gg, const float* __restrict__ gb,
    const float* __restrict__ cxr, float* __restrict__ cxw,
    float* __restrict__ h)
{
    const int wid = threadIdx.x >> 6, lane = threadIdx.x & 63;
    const int row = blockIdx.x * 4 + wid;     // nc*512 + vox, < 1024
    const int nc = row >> 9, vox = row & 511;
    const float* gr = k0 ? gsrc : gsrc + (size_t)row*256;
    float xi = gr[lane], xf = gr[64+lane], xc = gr[128+lane], xo = gr[192+lane];
    float mu = wred_sum(xi + xf + xc + xo) * (1.f/256.f);
    float di = xi-mu, df = xf-mu, dc = xc-mu, dq = xo-mu;
    float var = wred_sum(di*di + df*df + dc*dc + dq*dq) * (1.f/256.f);
    float rs = rsqrtf(var + 1e-5f);
    const float* gir = gi + ((size_t)(nc*7 + k)*512 + vox)*256;
    float Ig = gir[lane]     + di*rs*gg[lane]     + gb[lane];
    float Fg = gir[64+lane]  + df*rs*gg[64+lane]  + gb[64+lane];
    float Cg = gir[128+lane] + dc*rs*gg[128+lane] + gb[128+lane];
    float Og = gir[192+lane] + dq*rs*gg[192+lane] + gb[192+lane];
    float c_old = k0 ? 0.f : cxr[(size_t)row*64 + lane];
    float c_new = fsig(Fg) * c_old + fsig(Ig) * ftanh(Cg);
    float h_new = fsig(Og) * ftanh(c_new);
    cxw[(size_t)row*64 + lane] = c_new;
    h[((size_t)(nc*7 + k)*512 + vox)*64 + lane] = h_new;
}

// Head: 4 voxels per block, one wave per voxel.
__global__ __launch_bounds__(256) void head_kernel(
    const float* __restrict__ h,      // [2][7][512][64]
    const float* __restrict__ w1, const float* __restrict__ b1,
    const float* __restrict__ lng, const float* __restrict__ lnb,
    const float* __restrict__ w2, const float* __restrict__ b2,
    const int* __restrict__ ncode,
    float* __restrict__ out)
{
    __shared__ float zv[4][64];
    __shared__ float lg[4][512];
    const int blk = blockIdx.x;               // 768 = 2n * 3sn * 128 voxgroups
    const int n = blk / 384;
    const int sn = (blk / 128) % 3;
    const int vox0 = (blk & 127) * 4;
    const int wid = threadIdx.x >> 6, lane = threadIdx.x & 63;
    const int vox = vox0 + wid;
    const int r = (n*3 + sn)*512 + vox;       // pred row
    const float* hv = h + (size_t)((n*7 + sn + 4)*512 + vox)*64;

    // phase 1 (per wave): y = hv @ w1 + b1, LN, gelu
    float yv = b1[lane];
    for (int kk = 0; kk < 64; ++kk) yv = fmaf(hv[kk], w1[kk*64 + lane], yv);
    float mu = wred_sum(yv) * (1.f/64.f);
    float d = yv - mu;
    float var = wred_sum(d*d) * (1.f/64.f);
    float ln = d * rsqrtf(var + 1e-5f) * lng[lane] + lnb[lane];
    zv[wid][lane] = 0.5f * ln * (1.f + erff(ln * 0.70710678118654752f));

    // phase 2 (per wave): 8 couts per lane
    float l[8];
    #pragma unroll
    for (int j = 0; j < 8; ++j) l[j] = b2[j*64 + lane];
    for (int kk = 0; kk < 64; ++kk) {
        float zz = zv[wid][kk];
        #pragma unroll
        for (int j = 0; j < 8; ++j)
            l[j] = fmaf(zz, w2[kk*512 + j*64 + lane], l[j]);
    }
    #pragma unroll
    for (int j = 0; j < 8; ++j) lg[wid][j*64 + lane] = l[j];

    // argmax (first-max tiebreak) + softmax denom, per wave
    float m = l[0]; int mi = lane;
    #pragma unroll
    for (int j = 1; j < 8; ++j)
        if (l[j] > m) { m = l[j]; mi = j*64 + lane; }
    #pragma unroll
    for (int o = 32; o > 0; o >>= 1) {
        float om = __shfl_down(m, o, 64);
        int   oi = __shfl_down(mi, o, 64);
        if (om > m || (om == m && oi < mi)) { m = om; mi = oi; }
    }
    float maxv = __shfl(m, 0, 64);
    int   maxi = __shfl(mi, 0, 64);
    float es = 0.f;
    #pragma unroll
    for (int j = 0; j < 8; ++j) es += __expf(l[j] - maxv);
    float sum = wred_sum(es);
    if (lane == 0) {
        int target = ncode[(n*3 + sn)*512 + vox];
        float logp = lg[wid][target] - maxv - __logf(sum);
        atomicAdd(out + 1572864, -logp * (1.f/3072.f));
        out[1572865 + r] = (float)maxi;
    }

    // score write: transpose through LDS -> coalesced float4 on vox
    __syncthreads();
    const int t = threadIdx.x;
    #pragma unroll
    for (int jj = 0; jj < 2; ++jj) {
        int co = t + jj*256;
        float4 o4 = { lg[0][co], lg[1][co], lg[2][co], lg[3][co] };
        *(float4*)(out + (size_t)((n*512 + co)*3 + sn)*512 + vox0) = o4;
    }
}

extern "C" void kernel_launch(void* const* d_in, const int* in_sizes, int n_in,
                              void* d_out, int out_size, void* d_ws, size_t ws_size,
                              hipStream_t stream) {
    (void)in_sizes; (void)n_in; (void)out_size; (void)ws_size;
    const int*   code  = (const int*)d_in[0];
    const int*   ncode = (const int*)d_in[1];
    const float* emb   = (const float*)d_in[2];
    const float* win   = (const float*)d_in[3];
    const float* bin_  = (const float*)d_in[4];
    const float* gin_w = (const float*)d_in[5];
    const float* gin_b = (const float*)d_in[6];
    const float* wh    = (const float*)d_in[7];
    const float* bh    = (const float*)d_in[8];
    const float* gh_w  = (const float*)d_in[9];
    const float* gh_b  = (const float*)d_in[10];
    const float* w1    = (const float*)d_in[11];
    const float* b1    = (const float*)d_in[12];
    const float* ln_g  = (const float*)d_in[13];
    const float* ln_b  = (const float*)d_in[14];
    const float* w2    = (const float*)d_in[15];
    const float* b2    = (const float*)d_in[16];
    float* out = (float*)d_out;

    float* h    = (float*)d_ws;        // [2][7][512][64]   = 458752
    float* gi   = h + 458752;          // [2][7][512][256]  = 1835008
    float* gbuf0 = gi + 1835008;       // [2*512][256]      = 262144
    float* gbuf1 = gbuf0 + 262144;     // [2*512][256]      = 262144
    float* cbuf0 = gbuf1 + 262144;     // [2*512][64]       = 65536
    float* cbuf1 = cbuf0 + 65536;      // [2*512][64]       = 65536

    hipMemsetAsync(out + 1572864, 0, sizeof(float), stream);   // loss accumulator
    embed_kernel<<<1792, 256, 0, stream>>>(code, ncode, emb, h);

    for (int l = 0; l < 2; ++l) {
        conv_kernel<<<14*32, 256, 0, stream>>>(h, win + l*WSTRIDE, bin_ + l*256, gi);
        ln_kernel<<<1792, 256, 0, stream>>>(gi, gin_w + l*256, gin_b + l*256);
        for (int k = 0; k < 7; ++k) {
            const float* gsrc = (k == 0) ? (bh + l*256) : ((k & 1) ? gbuf1 : gbuf0);
            const float* cxr  = (k & 1) ? cbuf0 : cbuf1;   // cx_{k-1}
            float*       cxw  = (k & 1) ? cbuf1 : cbuf0;   // cx_k
            gates_kernel<<<256, 256, 0, stream>>>(gsrc, k == 0, k, gi,
                                                  gh_w + l*256, gh_b + l*256,
                                                  cxr, cxw, h);
            if (k < 6)
                conv_rec_kernel<<<256, 256, 0, stream>>>(h, k, wh + l*WSTRIDE,
                                                         bh + l*256,
                                                         (k & 1) ? gbuf0 : gbuf1);
        }
    }
    head_kernel<<<768, 256, 0, stream>>>(h, w1, b1, ln_g, ln_b, w2, b2, ncode, out);
}

// Round 5
// 981.582 us; speedup vs baseline: 1.2521x; 1.2521x over previous
//
#include <hip/hip_runtime.h>

// ConvLSTM fp32, round 5: occupancy-first convs.
// conv_kernel: per-du double-buffered xs (33.3 KB), weights direct from L2,
//   co split 8-way -> 896 blocks (~3.5/CU).
// conv_rec: v-split -> 512 blocks (2/CU), xs 37.6 KB, weights direct.

#define WSTRIDE 442368   // per-layer conv weight elements: 27*64*256

__device__ __forceinline__ float wred_sum(float v) {
    #pragma unroll
    for (int o = 32; o > 0; o >>= 1) v += __shfl_down(v, o, 64);
    return __shfl(v, 0, 64);
}
__device__ __forceinline__ float fsig(float x)  { return 1.f / (1.f + __expf(-x)); }
__device__ __forceinline__ float ftanh(float x) { return 1.f - 2.f / (__expf(2.f*x) + 1.f); }

// h[nc][s][vox][ch] = emb[tok][ch]
__global__ __launch_bounds__(256) void embed_kernel(
    const int* __restrict__ code, const int* __restrict__ ncode,
    const float* __restrict__ emb, float* __restrict__ h)
{
    int e = blockIdx.x * 256 + threadIdx.x;   // < 2*7*512*64 = 458752
    int ch = e & 63;
    int pos = e >> 6;            // nc*7*512 + s*512 + vox
    int vox = pos & 511;
    int t = pos >> 9;            // nc*7 + s
    int s = t % 7, nc = t / 7;
    int tok = (s < 5) ? code[(nc*5 + s)*512 + vox]
                      : ncode[(nc*3 + (s-5))*512 + vox];
    h[e] = emb[tok*64 + ch];
}

// 3x3x3 SAME conv, Cin=64 -> Cout=256, raw output + bias.
// x: [nslabs][512][64], wt: [27][64][256], y: [nslabs][512][256]
// grid = nslabs*8u*8cg = 896; block = (u-plane 64 vox) x (32 couts).
// xs double-buffered per du (33.3 KB); weights straight from L2 (wave-
// coalesced float4, ~1 TB/s total -- cheap). 1 barrier per du.
__global__ __launch_bounds__(256) void conv_kernel(
    const float* __restrict__ x, const float* __restrict__ wt,
    const float* __restrict__ bias, float* __restrict__ y)
{
    __shared__ float xs[2][64][65];                 // 33,280 B
    const int b = blockIdx.x;
    const int cg   = b & 7;
    const int u    = (b >> 3) & 7;
    const int slab = b >> 6;
    const int t = threadIdx.x;

    const float* plane = x + (size_t)(slab * 512) * 64;
    float4 ld[4];

    // load slab uu (zeros if OOB) into registers
    auto load_slab = [&](int uu) {
        const bool ok = (uu >= 0) && (uu < 8);
        const float4* p4 = (const float4*)(plane + uu * 64 * 64);
        #pragma unroll
        for (int p = 0; p < 4; ++p) {
            float4 v = {0.f, 0.f, 0.f, 0.f};
            if (ok) v = p4[p * 256 + t];
            ld[p] = v;
        }
    };
    // scatter registers into xs[buf][ci][vox]  (<=2-way bank aliasing: free)
    auto store_slab = [&](int buf) {
        #pragma unroll
        for (int p = 0; p < 4; ++p) {
            int q = p * 256 + t;
            int vox = q >> 4, ci0 = (q & 15) * 4;
            xs[buf][ci0 + 0][vox] = ld[p].x;
            xs[buf][ci0 + 1][vox] = ld[p].y;
            xs[buf][ci0 + 2][vox] = ld[p].z;
            xs[buf][ci0 + 3][vox] = ld[p].w;
        }
    };

    load_slab(u - 1);
    store_slab(0);
    load_slab(u);                       // in flight across du=0 compute

    const int co4 = t & 7, vg = t >> 3;
    const int co = cg * 32 + co4 * 4;
    const int vl = vg >> 2;             // 0..7
    const int w0 = (vg & 3) * 2;        // 0,2,4,6

    int xoff[12];
    #pragma unroll
    for (int dv = 0; dv < 3; ++dv)
        #pragma unroll
        for (int ww = 0; ww < 4; ++ww) {
            int vv = vl - 1 + dv, w = w0 - 1 + ww;
            xoff[dv * 4 + ww] =
                (vv >= 0 && vv < 8 && w >= 0 && w < 8) ? vv * 8 + w : -1;
        }

    float acc[4][2] = {};
    #pragma unroll
    for (int du = 0; du < 3; ++du) {
        __syncthreads();                          // xs[du&1] ready for all
        const float* xb = &xs[du & 1][0][0];
        const float* wp0 = wt + ((size_t)(du * 9) * 64) * 256 + co;
        for (int ci = 0; ci < 64; ++ci) {
            float xpv[12];
            #pragma unroll
            for (int q = 0; q < 12; ++q)
                xpv[q] = (xoff[q] >= 0) ? xb[ci * 65 + xoff[q]] : 0.f;
            const float* wp = wp0 + ci * 256;
            #pragma unroll
            for (int tap = 0; tap < 9; ++tap) {
                const float4 wv = *(const float4*)(wp + (size_t)tap * 16384);
                #pragma unroll
                for (int j = 0; j < 2; ++j) {
                    float xv = xpv[(tap / 3) * 4 + (tap % 3) + j];
                    acc[0][j] = fmaf(wv.x, xv, acc[0][j]);
                    acc[1][j] = fmaf(wv.y, xv, acc[1][j]);
                    acc[2][j] = fmaf(wv.z, xv, acc[2][j]);
                    acc[3][j] = fmaf(wv.w, xv, acc[3][j]);
                }
            }
        }
        if (du < 2) {
            store_slab((du + 1) & 1);   // other buffer: no barrier needed here
            if (du < 1) load_slab(u + 1);
        }
    }

    const float4 bv = *(const float4*)(bias + co);
    #pragma unroll
    for (int j = 0; j < 2; ++j) {
        int vox = vl * 8 + w0 + j;
        float4 o;
        o.x = acc[0][j] + bv.x; o.y = acc[1][j] + bv.y;
        o.z = acc[2][j] + bv.z; o.w = acc[3][j] + bv.w;
        *(float4*)(y + (size_t)((slab * 512 + u * 64 + vox) * 256 + co)) = o;
    }
}

// Recurrent conv: 2 slabs; grid = 2slab*8u*2vh*16cg = 512 (2/CU).
// Block = 32 vox (4 v-rows + halo) x 16 co, K(ci) split 4-way + LDS reduce.
// Weights direct from L2.
__global__ __launch_bounds__(256) void conv_rec_kernel(
    const float* __restrict__ h, int k,
    const float* __restrict__ wt,
    const float* __restrict__ bias, float* __restrict__ y)
{
    __shared__ float xs[3][64][49];      // 37,632 B; tile rows 6v x 8w
    const int b = blockIdx.x;            // 512
    const int cg   = b & 15;
    const int vh   = (b >> 4) & 1;
    const int u    = (b >> 5) & 7;
    const int slab = b >> 8;
    const int t = threadIdx.x;

    const float* plane = h + ((size_t)(slab * 7 + k) * 512) * 64;
    #pragma unroll
    for (int du = 0; du < 3; ++du) {
        const int uu = u - 1 + du;
        const bool uok = (uu >= 0) && (uu < 8);
        const float* pu = plane + uu * 64 * 64;
        #pragma unroll
        for (int p = 0; p < 3; ++p) {
            int q = p * 256 + t;            // 0..767
            int vl = q >> 7;                // 0..5
            int w = (q >> 4) & 7;
            int ci0 = (q & 15) * 4;
            int vgl = vh * 4 - 1 + vl;
            float4 v = {0.f, 0.f, 0.f, 0.f};
            if (uok && vgl >= 0 && vgl < 8)
                v = *(const float4*)(pu + (vgl * 8 + w) * 64 + ci0);
            xs[du][ci0 + 0][vl * 8 + w] = v.x;
            xs[du][ci0 + 1][vl * 8 + w] = v.y;
            xs[du][ci0 + 2][vl * 8 + w] = v.z;
            xs[du][ci0 + 3][vl * 8 + w] = v.w;
        }
    }

    const int kp = t >> 6;               // ci quarter
    const int lane = t & 63;
    const int coq = lane & 3, vg = lane >> 2;
    const int co = cg * 16 + coq * 4;
    const int vl = vg >> 2;              // 0..3 -> tile row vl+1
    const int w0 = (vg & 3) * 2;

    int xoff[12];
    #pragma unroll
    for (int dv = 0; dv < 3; ++dv)
        #pragma unroll
        for (int ww = 0; ww < 4; ++ww) {
            int w = w0 - 1 + ww;
            xoff[dv * 4 + ww] = (w >= 0 && w < 8) ? (vl + dv) * 8 + w : -1;
        }
    __syncthreads();

    float acc[4][2] = {};
    #pragma unroll
    for (int du = 0; du < 3; ++du) {
        const float* xb = &xs[du][0][0];
        const float* wp0 = wt + ((size_t)(du * 9) * 64 + kp * 16) * 256 + co;
        #pragma unroll 2
        for (int ci = 0; ci < 16; ++ci) {
            float xpv[12];
            #pragma unroll
            for (int q = 0; q < 12; ++q)
                xpv[q] = (xoff[q] >= 0) ? xb[(kp * 16 + ci) * 49 + xoff[q]] : 0.f;
            const float* wp = wp0 + ci * 256;
            #pragma unroll
            for (int tap = 0; tap < 9; ++tap) {
                const float4 wv = *(const float4*)(wp + (size_t)tap * 16384);
                #pragma unroll
                for (int j = 0; j < 2; ++j) {
                    float xv = xpv[(tap / 3) * 4 + (tap % 3) + j];
                    acc[0][j] = fmaf(wv.x, xv, acc[0][j]);
                    acc[1][j] = fmaf(wv.y, xv, acc[1][j]);
                    acc[2][j] = fmaf(wv.z, xv, acc[2][j]);
                    acc[3][j] = fmaf(wv.w, xv, acc[3][j]);
                }
            }
        }
    }
    __syncthreads();                     // xs reuse as reduction buffer
    float* red = &xs[0][0][0];           // 8*256 = 2048 floats
    #pragma unroll
    for (int a = 0; a < 4; ++a)
        #pragma unroll
        for (int j = 0; j < 2; ++j)
            red[(a * 2 + j) * 256 + t] = acc[a][j];
    __syncthreads();
    if (t < 64) {                        // kp==0 threads own the final sum
        const float4 bv = *(const float4*)(bias + co);
        float fin[8];
        #pragma unroll
        for (int i = 0; i < 8; ++i)
            fin[i] = red[i * 256 + t] + red[i * 256 + 64 + t]
                   + red[i * 256 + 128 + t] + red[i * 256 + 192 + t];
        #pragma unroll
        for (int j = 0; j < 2; ++j) {
            int vox = u * 64 + (vh * 4 + vl) * 8 + w0 + j;
            float4 o;
            o.x = fin[0 * 2 + j] + bv.x; o.y = fin[1 * 2 + j] + bv.y;
            o.z = fin[2 * 2 + j] + bv.z; o.w = fin[3 * 2 + j] + bv.w;
            *(float4*)(y + (size_t)((slab * 512 + vox) * 256 + co)) = o;
        }
    }
}

// In-place LayerNorm over 256 channels, one wave per row (4 rows/block).
__global__ __launch_bounds__(256) void ln_kernel(
    float* __restrict__ yio, const float* __restrict__ g,
    const float* __restrict__ b)
{
    const int wid = threadIdx.x >> 6, lane = threadIdx.x & 63;
    const int row = blockIdx.x * 4 + wid;
    float4 v = *(const float4*)(yio + (size_t)row*256 + lane*4);
    float mu = wred_sum(v.x + v.y + v.z + v.w) * (1.f/256.f);
    float4 d = { v.x-mu, v.y-mu, v.z-mu, v.w-mu };
    float var = wred_sum(d.x*d.x + d.y*d.y + d.z*d.z + d.w*d.w) * (1.f/256.f);
    float rs = rsqrtf(var + 1e-5f);
    float4 gv = *(const float4*)(g + lane*4);
    float4 bv = *(const float4*)(b + lane*4);
    float4 o = { d.x*rs*gv.x + bv.x, d.y*rs*gv.y + bv.y,
                 d.z*rs*gv.z + bv.z, d.w*rs*gv.w + bv.w };
    *(float4*)(yio + (size_t)row*256 + lane*4) = o;
}

// LSTM cell at step k: LN(gsrc) + gi[k] -> gates -> cx update -> h[., k].
// k0: gsrc is the 256-vector bh (ghat_0 = conv(0)+bh) and cx_old = 0.
__global__ __launch_bounds__(256) void gates_kernel(
    const float* __restrict__ gsrc, int k0, int k,
    const float* __restrict__ gi,
    const float* __restrict__ gg, const float* __restrict__ gb,
    const float* __restrict__ cxr, float* __restrict__ cxw,
    float* __restrict__ h)
{
    const int wid = threadIdx.x >> 6, lane = threadIdx.x & 63;
    const int row = blockIdx.x * 4 + wid;     // nc*512 + vox, < 1024
    const int nc = row >> 9, vox = row & 511;
    const float* gr = k0 ? gsrc : gsrc + (size_t)row*256;
    float xi = gr[lane], xf = gr[64+lane], xc = gr[128+lane], xo = gr[192+lane];
    float mu = wred_sum(xi + xf + xc + xo) * (1.f/256.f);
    float di = xi-mu, df = xf-mu, dc = xc-mu, dq = xo-mu;
    float var = wred_sum(di*di + df*df + dc*dc + dq*dq) * (1.f/256.f);
    float rs = rsqrtf(var + 1e-5f);
    const float* gir = gi + ((size_t)(nc*7 + k)*512 + vox)*256;
    float Ig = gir[lane]     + di*rs*gg[lane]     + gb[lane];
    float Fg = gir[64+lane]  + df*rs*gg[64+lane]  + gb[64+lane];
    float Cg = gir[128+lane] + dc*rs*gg[128+lane] + gb[128+lane];
    float Og = gir[192+lane] + dq*rs*gg[192+lane] + gb[192+lane];
    float c_old = k0 ? 0.f : cxr[(size_t)row*64 + lane];
    float c_new = fsig(Fg) * c_old + fsig(Ig) * ftanh(Cg);
    float h_new = fsig(Og) * ftanh(c_new);
    cxw[(size_t)row*64 + lane] = c_new;
    h[((size_t)(nc*7 + k)*512 + vox)*64 + lane] = h_new;
}

// Head: 4 voxels per block, one wave per voxel.
__global__ __launch_bounds__(256) void head_kernel(
    const float* __restrict__ h,      // [2][7][512][64]
    const float* __restrict__ w1, const float* __restrict__ b1,
    const float* __restrict__ lng, const float* __restrict__ lnb,
    const float* __restrict__ w2, const float* __restrict__ b2,
    const int* __restrict__ ncode,
    float* __restrict__ out)
{
    __shared__ float zv[4][64];
    __shared__ float lg[4][512];
    const int blk = blockIdx.x;               // 768 = 2n * 3sn * 128 voxgroups
    const int n = blk / 384;
    const int sn = (blk / 128) % 3;
    const int vox0 = (blk & 127) * 4;
    const int wid = threadIdx.x >> 6, lane = threadIdx.x & 63;
    const int vox = vox0 + wid;
    const int r = (n*3 + sn)*512 + vox;       // pred row
    const float* hv = h + (size_t)((n*7 + sn + 4)*512 + vox)*64;

    // phase 1 (per wave): y = hv @ w1 + b1, LN, gelu
    float yv = b1[lane];
    for (int kk = 0; kk < 64; ++kk) yv = fmaf(hv[kk], w1[kk*64 + lane], yv);
    float mu = wred_sum(yv) * (1.f/64.f);
    float d = yv - mu;
    float var = wred_sum(d*d) * (1.f/64.f);
    float ln = d * rsqrtf(var + 1e-5f) * lng[lane] + lnb[lane];
    zv[wid][lane] = 0.5f * ln * (1.f + erff(ln * 0.70710678118654752f));

    // phase 2 (per wave): 8 couts per lane
    float l[8];
    #pragma unroll
    for (int j = 0; j < 8; ++j) l[j] = b2[j*64 + lane];
    for (int kk = 0; kk < 64; ++kk) {
        float zz = zv[wid][kk];
        #pragma unroll
        for (int j = 0; j < 8; ++j)
            l[j] = fmaf(zz, w2[kk*512 + j*64 + lane], l[j]);
    }
    #pragma unroll
    for (int j = 0; j < 8; ++j) lg[wid][j*64 + lane] = l[j];

    // argmax (first-max tiebreak) + softmax denom, per wave
    float m = l[0]; int mi = lane;
    #pragma unroll
    for (int j = 1; j < 8; ++j)
        if (l[j] > m) { m = l[j]; mi = j*64 + lane; }
    #pragma unroll
    for (int o = 32; o > 0; o >>= 1) {
        float om = __shfl_down(m, o, 64);
        int   oi = __shfl_down(mi, o, 64);
        if (om > m || (om == m && oi < mi)) { m = om; mi = oi; }
    }
    float maxv = __shfl(m, 0, 64);
    int   maxi = __shfl(mi, 0, 64);
    float es = 0.f;
    #pragma unroll
    for (int j = 0; j < 8; ++j) es += __expf(l[j] - maxv);
    float sum = wred_sum(es);
    if (lane == 0) {
        int target = ncode[(n*3 + sn)*512 + vox];
        float logp = lg[wid][target] - maxv - __logf(sum);
        atomicAdd(out + 1572864, -logp * (1.f/3072.f));
        out[1572865 + r] = (float)maxi;
    }

    // score write: transpose through LDS -> coalesced float4 on vox
    __syncthreads();
    const int t = threadIdx.x;
    #pragma unroll
    for (int jj = 0; jj < 2; ++jj) {
        int co = t + jj*256;
        float4 o4 = { lg[0][co], lg[1][co], lg[2][co], lg[3][co] };
        *(float4*)(out + (size_t)((n*512 + co)*3 + sn)*512 + vox0) = o4;
    }
}

extern "C" void kernel_launch(void* const* d_in, const int* in_sizes, int n_in,
                              void* d_out, int out_size, void* d_ws, size_t ws_size,
                              hipStream_t stream) {
    (void)in_sizes; (void)n_in; (void)out_size; (void)ws_size;
    const int*   code  = (const int*)d_in[0];
    const int*   ncode = (const int*)d_in[1];
    const float* emb   = (const float*)d_in[2];
    const float* win   = (const float*)d_in[3];
    const float* bin_  = (const float*)d_in[4];
    const float* gin_w = (const float*)d_in[5];
    const float* gin_b = (const float*)d_in[6];
    const float* wh    = (const float*)d_in[7];
    const float* bh    = (const float*)d_in[8];
    const float* gh_w  = (const float*)d_in[9];
    const float* gh_b  = (const float*)d_in[10];
    const float* w1    = (const float*)d_in[11];
    const float* b1    = (const float*)d_in[12];
    const float* ln_g  = (const float*)d_in[13];
    const float* ln_b  = (const float*)d_in[14];
    const float* w2    = (const float*)d_in[15];
    const float* b2    = (const float*)d_in[16];
    float* out = (float*)d_out;

    float* h    = (float*)d_ws;        // [2][7][512][64]   = 458752
    float* gi   = h + 458752;          // [2][7][512][256]  = 1835008
    float* gbuf0 = gi + 1835008;       // [2*512][256]      = 262144
    float* gbuf1 = gbuf0 + 262144;     // [2*512][256]      = 262144
    float* cbuf0 = gbuf1 + 262144;     // [2*512][64]       = 65536
    float* cbuf1 = cbuf0 + 65536;      // [2*512][64]       = 65536

    hipMemsetAsync(out + 1572864, 0, sizeof(float), stream);   // loss accumulator
    embed_kernel<<<1792, 256, 0, stream>>>(code, ncode, emb, h);

    for (int l = 0; l < 2; ++l) {
        conv_kernel<<<896, 256, 0, stream>>>(h, win + l*WSTRIDE, bin_ + l*256, gi);
        ln_kernel<<<1792, 256, 0, stream>>>(gi, gin_w + l*256, gin_b + l*256);
        for (int k = 0; k < 7; ++k) {
            const float* gsrc = (k == 0) ? (bh + l*256) : ((k & 1) ? gbuf1 : gbuf0);
            const float* cxr  = (k & 1) ? cbuf0 : cbuf1;   // cx_{k-1}
            float*       cxw  = (k & 1) ? cbuf1 : cbuf0;   // cx_k
            gates_kernel<<<256, 256, 0, stream>>>(gsrc, k == 0, k, gi,
                                                  gh_w + l*256, gh_b + l*256,
                                                  cxr, cxw, h);
            if (k < 6)
                conv_rec_kernel<<<512, 256, 0, stream>>>(h, k, wh + l*WSTRIDE,
                                                         bh + l*256,
                                                         (k & 1) ? gbuf0 : gbuf1);
        }
    }
    head_kernel<<<768, 256, 0, stream>>>(h, w1, b1, ln_g, ln_b, w2, b2, ncode, out);
}

// Round 6
// 865.111 us; speedup vs baseline: 1.4207x; 1.1346x over previous
//
#include <hip/hip_runtime.h>

// ConvLSTM fp32, round 6: conv inner loop rebuilt from the LDS-pipe model.
// x: halo-padded LDS (zero-filled, 8 ds_read_b64/ci, no selects), 16-ci
// double-buffered chunks; weights: global -> 2-deep register pipeline
// (wv[2][9] float4, prefetch ci+1 during ci's 144 FMAs).

#define WSTRIDE 442368   // per-layer conv weight elements: 27*64*256

__device__ __forceinline__ float wred_sum(float v) {
    #pragma unroll
    for (int o = 32; o > 0; o >>= 1) v += __shfl_down(v, o, 64);
    return __shfl(v, 0, 64);
}
__device__ __forceinline__ float fsig(float x)  { return 1.f / (1.f + __expf(-x)); }
__device__ __forceinline__ float ftanh(float x) { return 1.f - 2.f / (__expf(2.f*x) + 1.f); }

// h[nc][s][vox][ch] = emb[tok][ch]
__global__ __launch_bounds__(256) void embed_kernel(
    const int* __restrict__ code, const int* __restrict__ ncode,
    const float* __restrict__ emb, float* __restrict__ h)
{
    int e = blockIdx.x * 256 + threadIdx.x;   // < 2*7*512*64 = 458752
    int ch = e & 63;
    int pos = e >> 6;            // nc*7*512 + s*512 + vox
    int vox = pos & 511;
    int t = pos >> 9;            // nc*7 + s
    int s = t % 7, nc = t / 7;
    int tok = (s < 5) ? code[(nc*5 + s)*512 + vox]
                      : ncode[(nc*3 + (s-5))*512 + vox];
    h[e] = emb[tok*64 + ch];
}

// 3x3x3 SAME conv, Cin=64 -> Cout=256, raw output + bias.
// x: [nslabs][512][64], wt: [27][64][256], y: [nslabs][512][256]
// grid = 14 slab * 8 u * 4 cg = 448; block = full u-plane (64 vox) x 64 co.
// thread = (coq 16 -> 4 co, vg 16 -> 2x2 vox patch); acc[4co][4vox].
__global__ __launch_bounds__(256) void conv_kernel(
    const float* __restrict__ x, const float* __restrict__ wt,
    const float* __restrict__ bias, float* __restrict__ y)
{
    __shared__ float xs[2][16][10][14];   // halo'd: row r -> v=r-1, idx -> w=idx-1
    const int b = blockIdx.x;
    const int cg   = b & 3;
    const int u    = (b >> 2) & 7;
    const int slab = b >> 5;
    const int t = threadIdx.x;

    const int coq = t & 15, vg = t >> 4;
    const int co = cg*64 + coq*4;
    const int v0 = (vg >> 2) * 2;         // 0,2,4,6
    const int w0 = (vg & 3) * 2;          // 0,2,4,6

    const float* xbase = x + (size_t)(slab*512)*64;

    float4 sreg[2];
    // chunk c: du = c>>2 (slab u-1..u+1), cb = c&3 (ci block of 16)
    auto stage_load = [&](int c) {
        const int du = c >> 2, cb = c & 3;
        const int uu = u + du - 1;
        #pragma unroll
        for (int p = 0; p < 2; ++p) {
            int s = p*256 + t;
            float4 v = {0.f, 0.f, 0.f, 0.f};
            if (s < 480) {
                int r = s / 48, rem = s % 48;
                int idx = rem >> 2, ci4 = rem & 3;
                if (uu >= 0 && uu < 8 && r >= 1 && r <= 8 && idx >= 1 && idx <= 8)
                    v = *(const float4*)(xbase +
                        (size_t)(uu*64 + (r-1)*8 + (idx-1))*64 + cb*16 + ci4*4);
            }
            sreg[p] = v;
        }
    };
    auto stage_store = [&](int buf) {
        #pragma unroll
        for (int p = 0; p < 2; ++p) {
            int s = p*256 + t;
            if (s < 480) {
                int r = s / 48, rem = s % 48;
                int idx = rem >> 2, ci4 = rem & 3;
                xs[buf][ci4*4+0][r][idx] = sreg[p].x;
                xs[buf][ci4*4+1][r][idx] = sreg[p].y;
                xs[buf][ci4*4+2][r][idx] = sreg[p].z;
                xs[buf][ci4*4+3][r][idx] = sreg[p].w;
            }
        }
    };

    float4 wv[2][9];
    // flat k = 0..191: du = k>>6, gci = ((k>>4)&3)*16 + (k&15)
    auto wload = [&](int k, int wb) {
        int du = k >> 6;
        int gci = ((k >> 4) & 3)*16 + (k & 15);
        const float* wp = wt + ((size_t)(du*9)*64 + gci)*256 + co;
        #pragma unroll
        for (int tap = 0; tap < 9; ++tap)
            wv[wb][tap] = *(const float4*)(wp + (size_t)tap*16384);
    };

    stage_load(0);
    stage_store(0);
    wload(0, 0);
    __syncthreads();

    float acc[4][4] = {};
    for (int c = 0; c < 12; ++c) {
        const int buf = c & 1;
        if (c < 11) stage_load(c + 1);    // long-latency, lands before store
        #pragma unroll 2
        for (int cl = 0; cl < 16; ++cl) {
            const int k = c*16 + cl;
            if (k < 191) wload(k + 1, (k + 1) & 1);
            float xpv[4][4];
            #pragma unroll
            for (int a = 0; a < 4; ++a) {
                const float2* xr = (const float2*)&xs[buf][cl][v0 + a][w0];
                float2 lo = xr[0], hi = xr[1];
                xpv[a][0] = lo.x; xpv[a][1] = lo.y;
                xpv[a][2] = hi.x; xpv[a][3] = hi.y;
            }
            const float4* wc = wv[k & 1];
            #pragma unroll
            for (int dv = 0; dv < 3; ++dv)
                #pragma unroll
                for (int dw = 0; dw < 3; ++dw) {
                    const float4 wq = wc[dv*3 + dw];
                    #pragma unroll
                    for (int j = 0; j < 4; ++j) {
                        float xv = xpv[(j>>1) + dv][(j&1) + dw];
                        acc[0][j] = fmaf(wq.x, xv, acc[0][j]);
                        acc[1][j] = fmaf(wq.y, xv, acc[1][j]);
                        acc[2][j] = fmaf(wq.z, xv, acc[2][j]);
                        acc[3][j] = fmaf(wq.w, xv, acc[3][j]);
                    }
                }
        }
        if (c < 11) stage_store((c + 1) & 1);
        __syncthreads();
    }

    const float4 bv = *(const float4*)(bias + co);
    #pragma unroll
    for (int j = 0; j < 4; ++j) {
        int vox = (v0 + (j>>1))*8 + w0 + (j&1);
        float4 o;
        o.x = acc[0][j] + bv.x; o.y = acc[1][j] + bv.y;
        o.z = acc[2][j] + bv.z; o.w = acc[3][j] + bv.w;
        *(float4*)(y + (size_t)((slab*512 + u*64 + vox)*256 + co)) = o;
    }
}

// Recurrent conv: grid = 2 slab * 8 u * 2 vh * 16 cg = 512 (2/CU).
// Block = half-plane (32 vox) x 16 co, K(ci) split 4-way + LDS reduce.
// Same x-halo-LDS + weight register pipeline structure.
__global__ __launch_bounds__(256) void conv_rec_kernel(
    const float* __restrict__ h, int kstep,
    const float* __restrict__ wt,
    const float* __restrict__ bias, float* __restrict__ y)
{
    __shared__ float xs[2][16][6][14];    // rows r -> v = vh*4 + r - 1
    const int b = blockIdx.x;             // 512
    const int cg   = b & 15;
    const int vh   = (b >> 4) & 1;
    const int u    = (b >> 5) & 7;
    const int slab = b >> 8;
    const int t = threadIdx.x;

    const int kp = t >> 6;                // ci quarter
    const int lane = t & 63;
    const int coq = lane & 3, vg = lane >> 2;
    const int co = cg*16 + coq*4;
    const int pv = vg >> 2;               // local v row 0..3
    const int w0 = (vg & 3) * 2;          // 0,2,4,6

    const float* xbase = h + ((size_t)(slab*7 + kstep)*512)*64;

    float4 sreg[2];
    // chunk c: du = c>>2, cq = c&3; slot sl = kp4*4 + cc; gci = kp4*16 + cq*4 + cc
    auto stage_load = [&](int c) {
        const int du = c >> 2, cq = c & 3;
        const int uu = u + du - 1;
        #pragma unroll
        for (int p = 0; p < 2; ++p) {
            int s = p*256 + t;
            float4 v = {0.f, 0.f, 0.f, 0.f};
            if (s < 288) {
                int r = s / 48, rem = s % 48;
                int idx = rem >> 2, kp4 = rem & 3;
                int gv = vh*4 + r - 1;
                if (uu >= 0 && uu < 8 && gv >= 0 && gv < 8 && idx >= 1 && idx <= 8)
                    v = *(const float4*)(xbase +
                        (size_t)(uu*64 + gv*8 + (idx-1))*64 + kp4*16 + cq*4);
            }
            sreg[p] = v;
        }
    };
    auto stage_store = [&](int buf) {
        #pragma unroll
        for (int p = 0; p < 2; ++p) {
            int s = p*256 + t;
            if (s < 288) {
                int r = s / 48, rem = s % 48;
                int idx = rem >> 2, kp4 = rem & 3;
                xs[buf][kp4*4+0][r][idx] = sreg[p].x;
                xs[buf][kp4*4+1][r][idx] = sreg[p].y;
                xs[buf][kp4*4+2][r][idx] = sreg[p].z;
                xs[buf][kp4*4+3][r][idx] = sreg[p].w;
            }
        }
    };

    float4 wv[2][9];
    // flat n = 0..47: du = n>>4, cq = (n>>2)&3, i = n&3; gci = kp*16 + cq*4 + i
    auto wload = [&](int n, int wb) {
        int du = n >> 4;
        int gci = kp*16 + ((n >> 2) & 3)*4 + (n & 3);
        const float* wp = wt + ((size_t)(du*9)*64 + gci)*256 + co;
        #pragma unroll
        for (int tap = 0; tap < 9; ++tap)
            wv[wb][tap] = *(const float4*)(wp + (size_t)tap*16384);
    };

    stage_load(0);
    stage_store(0);
    wload(0, 0);
    __syncthreads();

    float acc[4][2] = {};
    for (int c = 0; c < 12; ++c) {
        const int buf = c & 1;
        if (c < 11) stage_load(c + 1);
        #pragma unroll 2
        for (int i = 0; i < 4; ++i) {
            const int n = c*4 + i;
            if (n < 47) wload(n + 1, (n + 1) & 1);
            const int cl = kp*4 + i;      // LDS slot
            float xpv[3][4];
            #pragma unroll
            for (int a = 0; a < 3; ++a) {
                const float2* xr = (const float2*)&xs[buf][cl][pv + a][w0];
                float2 lo = xr[0], hi = xr[1];
                xpv[a][0] = lo.x; xpv[a][1] = lo.y;
                xpv[a][2] = hi.x; xpv[a][3] = hi.y;
            }
            const float4* wc = wv[n & 1];
            #pragma unroll
            for (int dv = 0; dv < 3; ++dv)
                #pragma unroll
                for (int dw = 0; dw < 3; ++dw) {
                    const float4 wq = wc[dv*3 + dw];
                    #pragma unroll
                    for (int j = 0; j < 2; ++j) {
                        float xv = xpv[dv][j + dw];
                        acc[0][j] = fmaf(wq.x, xv, acc[0][j]);
                        acc[1][j] = fmaf(wq.y, xv, acc[1][j]);
                        acc[2][j] = fmaf(wq.z, xv, acc[2][j]);
                        acc[3][j] = fmaf(wq.w, xv, acc[3][j]);
                    }
                }
        }
        if (c < 11) stage_store((c + 1) & 1);
        __syncthreads();
    }

    // K-reduction: xs (2688 floats) reused as red[8][256]
    float* red = &xs[0][0][0][0];
    #pragma unroll
    for (int a = 0; a < 4; ++a)
        #pragma unroll
        for (int j = 0; j < 2; ++j)
            red[(a*2 + j)*256 + t] = acc[a][j];
    __syncthreads();
    if (t < 64) {                         // kp==0 threads own the final sum
        const float4 bv = *(const float4*)(bias + co);
        float fin[8];
        #pragma unroll
        for (int i = 0; i < 8; ++i)
            fin[i] = red[i*256 + t] + red[i*256 + 64 + t]
                   + red[i*256 + 128 + t] + red[i*256 + 192 + t];
        #pragma unroll
        for (int j = 0; j < 2; ++j) {
            int vox = u*64 + (vh*4 + pv)*8 + w0 + j;
            float4 o;
            o.x = fin[0*2 + j] + bv.x; o.y = fin[1*2 + j] + bv.y;
            o.z = fin[2*2 + j] + bv.z; o.w = fin[3*2 + j] + bv.w;
            *(float4*)(y + (size_t)((slab*512 + vox)*256 + co)) = o;
        }
    }
}

// In-place LayerNorm over 256 channels, one wave per row (4 rows/block).
__global__ __launch_bounds__(256) void ln_kernel(
    float* __restrict__ yio, const float* __restrict__ g,
    const float* __restrict__ b)
{
    const int wid = threadIdx.x >> 6, lane = threadIdx.x & 63;
    const int row = blockIdx.x * 4 + wid;
    float4 v = *(const float4*)(yio + (size_t)row*256 + lane*4);
    float mu = wred_sum(v.x + v.y + v.z + v.w) * (1.f/256.f);
    float4 d = { v.x-mu, v.y-mu, v.z-mu, v.w-mu };
    float var = wred_sum(d.x*d.x + d.y*d.y + d.z*d.z + d.w*d.w) * (1.f/256.f);
    float rs = rsqrtf(var + 1e-5f);
    float4 gv = *(const float4*)(g + lane*4);
    float4 bv = *(const float4*)(b + lane*4);
    float4 o = { d.x*rs*gv.x + bv.x, d.y*rs*gv.y + bv.y,
                 d.z*rs*gv.z + bv.z, d.w*rs*gv.w + bv.w };
    *(float4*)(yio + (size_t)row*256 + lane*4) = o;
}

// LSTM cell at step k: LN(gsrc) + gi[k] -> gates -> cx update -> h[., k].
// k0: gsrc is the 256-vector bh (ghat_0 = conv(0)+bh) and cx_old = 0.
__global__ __launch_bounds__(256) void gates_kernel(
    const float* __restrict__ gsrc, int k0, int k,
    const float* __restrict__ gi,
    const float* __restrict__ gg, const float* __restrict__ gb,
    const float* __restrict__ cxr, float* __restrict__ cxw,
    float* __restrict__ h)
{
    const int wid = threadIdx.x >> 6, lane = threadIdx.x & 63;
    const int row = blockIdx.x * 4 + wid;     // nc*512 + vox, < 1024
    const int nc = row >> 9, vox = row & 511;
    const float* gr = k0 ? gsrc : gsrc + (size_t)row*256;
    float xi = gr[lane], xf = gr[64+lane], xc = gr[128+lane], xo = gr[192+lane];
    float mu = wred_sum(xi + xf + xc + xo) * (1.f/256.f);
    float di = xi-mu, df = xf-mu, dc = xc-mu, dq = xo-mu;
    float var = wred_sum(di*di + df*df + dc*dc + dq*dq) * (1.f/256.f);
    float rs = rsqrtf(var + 1e-5f);
    const float* gir = gi + ((size_t)(nc*7 + k)*512 + vox)*256;
    float Ig = gir[lane]     + di*rs*gg[lane]     + gb[lane];
    float Fg = gir[64+lane]  + df*rs*gg[64+lane]  + gb[64+lane];
    float Cg = gir[128+lane] + dc*rs*gg[128+lane] + gb[128+lane];
    float Og = gir[192+lane] + dq*rs*gg[192+lane] + gb[192+lane];
    float c_old = k0 ? 0.f : cxr[(size_t)row*64 + lane];
    float c_new = fsig(Fg) * c_old + fsig(Ig) * ftanh(Cg);
    float h_new = fsig(Og) * ftanh(c_new);
    cxw[(size_t)row*64 + lane] = c_new;
    h[((size_t)(nc*7 + k)*512 + vox)*64 + lane] = h_new;
}

// Head: 4 voxels per block, one wave per voxel.
__global__ __launch_bounds__(256) void head_kernel(
    const float* __restrict__ h,      // [2][7][512][64]
    const float* __restrict__ w1, const float* __restrict__ b1,
    const float* __restrict__ lng, const float* __restrict__ lnb,
    const float* __restrict__ w2, const float* __restrict__ b2,
    const int* __restrict__ ncode,
    float* __restrict__ out)
{
    __shared__ float zv[4][64];
    __shared__ float lg[4][512];
    const int blk = blockIdx.x;               // 768 = 2n * 3sn * 128 voxgroups
    const int n = blk / 384;
    const int sn = (blk / 128) % 3;
    const int vox0 = (blk & 127) * 4;
    const int wid = threadIdx.x >> 6, lane = threadIdx.x & 63;
    const int vox = vox0 + wid;
    const int r = (n*3 + sn)*512 + vox;       // pred row
    const float* hv = h + (size_t)((n*7 + sn + 4)*512 + vox)*64;

    // phase 1 (per wave): y = hv @ w1 + b1, LN, gelu
    float yv = b1[lane];
    for (int kk = 0; kk < 64; ++kk) yv = fmaf(hv[kk], w1[kk*64 + lane], yv);
    float mu = wred_sum(yv) * (1.f/64.f);
    float d = yv - mu;
    float var = wred_sum(d*d) * (1.f/64.f);
    float ln = d * rsqrtf(var + 1e-5f) * lng[lane] + lnb[lane];
    zv[wid][lane] = 0.5f * ln * (1.f + erff(ln * 0.70710678118654752f));

    // phase 2 (per wave): 8 couts per lane
    float l[8];
    #pragma unroll
    for (int j = 0; j < 8; ++j) l[j] = b2[j*64 + lane];
    for (int kk = 0; kk < 64; ++kk) {
        float zz = zv[wid][kk];
        #pragma unroll
        for (int j = 0; j < 8; ++j)
            l[j] = fmaf(zz, w2[kk*512 + j*64 + lane], l[j]);
    }
    #pragma unroll
    for (int j = 0; j < 8; ++j) lg[wid][j*64 + lane] = l[j];

    // argmax (first-max tiebreak) + softmax denom, per wave
    float m = l[0]; int mi = lane;
    #pragma unroll
    for (int j = 1; j < 8; ++j)
        if (l[j] > m) { m = l[j]; mi = j*64 + lane; }
    #pragma unroll
    for (int o = 32; o > 0; o >>= 1) {
        float om = __shfl_down(m, o, 64);
        int   oi = __shfl_down(mi, o, 64);
        if (om > m || (om == m && oi < mi)) { m = om; mi = oi; }
    }
    float maxv = __shfl(m, 0, 64);
    int   maxi = __shfl(mi, 0, 64);
    float es = 0.f;
    #pragma unroll
    for (int j = 0; j < 8; ++j) es += __expf(l[j] - maxv);
    float sum = wred_sum(es);
    if (lane == 0) {
        int target = ncode[(n*3 + sn)*512 + vox];
        float logp = lg[wid][target] - maxv - __logf(sum);
        atomicAdd(out + 1572864, -logp * (1.f/3072.f));
        out[1572865 + r] = (float)maxi;
    }

    // score write: transpose through LDS -> coalesced float4 on vox
    __syncthreads();
    const int t = threadIdx.x;
    #pragma unroll
    for (int jj = 0; jj < 2; ++jj) {
        int co = t + jj*256;
        float4 o4 = { lg[0][co], lg[1][co], lg[2][co], lg[3][co] };
        *(float4*)(out + (size_t)((n*512 + co)*3 + sn)*512 + vox0) = o4;
    }
}

extern "C" void kernel_launch(void* const* d_in, const int* in_sizes, int n_in,
                              void* d_out, int out_size, void* d_ws, size_t ws_size,
                              hipStream_t stream) {
    (void)in_sizes; (void)n_in; (void)out_size; (void)ws_size;
    const int*   code  = (const int*)d_in[0];
    const int*   ncode = (const int*)d_in[1];
    const float* emb   = (const float*)d_in[2];
    const float* win   = (const float*)d_in[3];
    const float* bin_  = (const float*)d_in[4];
    const float* gin_w = (const float*)d_in[5];
    const float* gin_b = (const float*)d_in[6];
    const float* wh    = (const float*)d_in[7];
    const float* bh    = (const float*)d_in[8];
    const float* gh_w  = (const float*)d_in[9];
    const float* gh_b  = (const float*)d_in[10];
    const float* w1    = (const float*)d_in[11];
    const float* b1    = (const float*)d_in[12];
    const float* ln_g  = (const float*)d_in[13];
    const float* ln_b  = (const float*)d_in[14];
    const float* w2    = (const float*)d_in[15];
    const float* b2    = (const float*)d_in[16];
    float* out = (float*)d_out;

    float* h    = (float*)d_ws;        // [2][7][512][64]   = 458752
    float* gi   = h + 458752;          // [2][7][512][256]  = 1835008
    float* gbuf0 = gi + 1835008;       // [2*512][256]      = 262144
    float* gbuf1 = gbuf0 + 262144;     // [2*512][256]      = 262144
    float* cbuf0 = gbuf1 + 262144;     // [2*512][64]       = 65536
    float* cbuf1 = cbuf0 + 65536;      // [2*512][64]       = 65536

    hipMemsetAsync(out + 1572864, 0, sizeof(float), stream);   // loss accumulator
    embed_kernel<<<1792, 256, 0, stream>>>(code, ncode, emb, h);

    for (int l = 0; l < 2; ++l) {
        conv_kernel<<<448, 256, 0, stream>>>(h, win + l*WSTRIDE, bin_ + l*256, gi);
        ln_kernel<<<1792, 256, 0, stream>>>(gi, gin_w + l*256, gin_b + l*256);
        for (int k = 0; k < 7; ++k) {
            const float* gsrc = (k == 0) ? (bh + l*256) : ((k & 1) ? gbuf1 : gbuf0);
            const float* cxr  = (k & 1) ? cbuf0 : cbuf1;   // cx_{k-1}
            float*       cxw  = (k & 1) ? cbuf1 : cbuf0;   // cx_k
            gates_kernel<<<256, 256, 0, stream>>>(gsrc, k == 0, k, gi,
                                                  gh_w + l*256, gh_b + l*256,
                                                  cxr, cxw, h);
            if (k < 6)
                conv_rec_kernel<<<512, 256, 0, stream>>>(h, k, wh + l*WSTRIDE,
                                                         bh + l*256,
                                                         (k & 1) ? gbuf0 : gbuf1);
        }
    }
    head_kernel<<<768, 256, 0, stream>>>(h, w1, b1, ln_g, ln_b, w2, b2, ncode, out);
}